// Round 13
// baseline (112.320 us; speedup 1.0000x reference)
//
#include <hip/hip_runtime.h>

#define D  128   // EMB
#define KN 128   // K_N
#define NB 8     // batch rows per block (grid = 512 -> 2 blocks/CU)
#define LOG2E 1.44269504088896340736f

typedef float f32x4  __attribute__((ext_vector_type(4)));
typedef float f32x16 __attribute__((ext_vector_type(16)));
typedef short s16x8  __attribute__((ext_vector_type(8)));   // 8 bf16 (4 VGPR)

__device__ __forceinline__ float negexp(float v) {              // e^{-v}
    return __builtin_amdgcn_exp2f(v * -LOG2E);
}
__device__ __forceinline__ float sigf(float x) {                // sigmoid
    return __builtin_amdgcn_rcpf(1.0f + negexp(x));
}
__device__ __forceinline__ unsigned short f2bf(float f) {       // fp32->bf16 RNE
    unsigned u = __float_as_uint(f);
    return (unsigned short)((u + 0x7fffu + ((u >> 16) & 1u)) >> 16);
}
__device__ __forceinline__ float bf2f(unsigned short u) {
    return __uint_as_float(((unsigned)u) << 16);
}
__device__ __forceinline__ s16x8 pack8(float4 a, float4 b) {
    s16x8 r;
    r[0]=(short)f2bf(a.x); r[1]=(short)f2bf(a.y); r[2]=(short)f2bf(a.z); r[3]=(short)f2bf(a.w);
    r[4]=(short)f2bf(b.x); r[5]=(short)f2bf(b.y); r[6]=(short)f2bf(b.z); r[7]=(short)f2bf(b.w);
    return r;
}
__device__ __forceinline__ s16x8 pack8abs(float4 a, float4 b) {
    s16x8 r;
    r[0]=(short)f2bf(fabsf(a.x)); r[1]=(short)f2bf(fabsf(a.y)); r[2]=(short)f2bf(fabsf(a.z)); r[3]=(short)f2bf(fabsf(a.w));
    r[4]=(short)f2bf(fabsf(b.x)); r[5]=(short)f2bf(fabsf(b.y)); r[6]=(short)f2bf(fabsf(b.z)); r[7]=(short)f2bf(fabsf(b.w));
    return r;
}

// phase-B core: 2 elements (k=2l,2l+1) of one (b,e)
#define CORE(EA1, EA2, T, PZ, A0, A1) do {                                   \
    float x0_ = fmaf((EA1), (T).x, 1.0f);                                    \
    float x1_ = fmaf((EA1), (T).y, 1.0f);                                    \
    float y0_ = fmaf((EA2), (T).z, 1.0f);                                    \
    float y1_ = fmaf((EA2), (T).w, 1.0f);                                    \
    (A0) = fmaf((y0_ - x0_) * (PZ), __builtin_amdgcn_rcpf(x0_ * y0_), (A0)); \
    (A1) = fmaf((y1_ - x1_) * (PZ), __builtin_amdgcn_rcpf(x1_ * y1_), (A1)); \
} while (0)

__global__ __launch_bounds__(512, 4) void fused_kernel(
    const int* __restrict__ stu_id, const int* __restrict__ exer_id,
    const float* __restrict__ kq,
    const float* __restrict__ stu_q, const float* __restrict__ exer_k,
    const float* __restrict__ stu_v, const float* __restrict__ exer_v,
    const float* __restrict__ kn,
    const float* __restrict__ W1, const float* __restrict__ b1,
    const float* __restrict__ W2, const float* __restrict__ b2,
    const float* __restrict__ W3, const float* __restrict__ b3,
    float* __restrict__ out, int B)
{
    // LDS map (77824 B -> 2 blocks/CU):
    //   [0,65536)     TAB bf16 ushort4[e][lane] = {E1(2l),E1(2l+1),E2(2l),E2(2l+1)}
    //                 epilogue alias: RED float2[8][8][64] = 32 KB at [0,32768)
    //   [65536,73728) EAf fp32: b*256 + 2e + {0,1}
    //   [73728,77824) PZf fp32: r*128 + e
    __shared__ __align__(16) char smemraw[77824];

    unsigned short* TABh  = (unsigned short*)smemraw;
    const ushort4*  TABh4 = (const ushort4*)smemraw;
    float* EAf = (float*)(smemraw + 65536);
    float* PZf = (float*)(smemraw + 73728);

    const int tid  = threadIdx.x;
    const int b0   = blockIdx.x * NB;
    const int lane = tid & 63, wid = tid >> 6;     // 8 waves
    const int l31 = lane & 31, g32 = lane >> 5;
    const int l15 = lane & 15, g16 = lane >> 4;
    const int bmax = B - 1;

    // ---- tables GEMM, no LDS staging: B-frags (kn) packed ONCE into regs ----
    // wave w: set = w>>2 (W1|W2), kt = w&3 -> k-rows [32kt, 32kt+32)
    // 4 passes p = et: one f32x16 acc live at a time (16 AGPR)
    const float* Wt   = (wid < 4) ? W1 : W2;
    const float* bias = (wid < 4) ? b1 : b2;
    const int slot = (wid < 4) ? 0 : 2;
    const int krow = (wid & 3) * 32 + l31;
    const int kof  = ((krow >> 1) << 2) + (krow & 1) + slot;   // TAB col offset

    s16x8 bf[8];
    #pragma unroll
    for (int q = 0; q < 8; ++q) {
        const float4* pk = (const float4*)(kn + (size_t)krow * D + q * 16 + g32 * 8);
        bf[q] = pack8(pk[0], pk[1]);
    }

    #pragma unroll 1
    for (int p = 0; p < 4; ++p) {
        f32x16 acc = {0};
        const int er = p * 32 + l31;
        #pragma unroll
        for (int q = 0; q < 8; ++q) {
            const float4* pw = (const float4*)(Wt + (size_t)er * (2 * D) + D + q * 16 + g32 * 8);
            acc = __builtin_amdgcn_mfma_f32_32x32x16_bf16(
                pack8abs(pw[0], pw[1]), bf[q], acc, 0, 0, 0);
        }
        // write: C row e = p*32 + (r&3) + 8*(r>>2) + 4*g32, col k = krow (m74)
        #pragma unroll
        for (int r = 0; r < 16; ++r) {
            int e_ = p * 32 + (r & 3) + ((r >> 2) << 3) + (g32 << 2);
            TABh[e_ * 256 + kof] = f2bf(negexp(acc[r] + bias[e_]));
        }
    }

    // ---- prep GEMM: C[8b x 16e], e-tile = wid; A rows 8-15 dup of 0-7 ----
    {
        int bb = b0 + (l15 & 7); bb = bb <= bmax ? bb : bmax;
        const int sid_l = stu_id[bb], eid_l = exer_id[bb];
        const int erow = wid * 16 + l15;
        f32x4 accS = {0, 0, 0, 0}, accE = {0, 0, 0, 0};
        #pragma unroll 1
        for (int q = 0; q < 4; ++q) {
            int d = q * 32 + g16 * 8;
            const float4* pa = (const float4*)(stu_v + (size_t)sid_l * D + d);
            const float4* pe = (const float4*)(exer_v + (size_t)eid_l * D + d);
            const float4* pb = (const float4*)(W1 + (size_t)erow * (2 * D) + d);
            const float4* pc = (const float4*)(W2 + (size_t)erow * (2 * D) + d);
            accS = __builtin_amdgcn_mfma_f32_16x16x32_bf16(
                pack8(pa[0], pa[1]), pack8abs(pb[0], pb[1]), accS, 0, 0, 0);
            accE = __builtin_amdgcn_mfma_f32_16x16x32_bf16(
                pack8(pe[0], pe[1]), pack8abs(pc[0], pc[1]), accE, 0, 0, 0);
        }
        #pragma unroll
        for (int r = 0; r < 4; ++r) {              // C row = g16*4+r, col e = erow
            int brow = g16 * 4 + r;
            if (brow < NB) {
                int eo = brow * 256 + 2 * erow;
                EAf[eo]     = negexp(accS[r]);
                EAf[eo + 1] = negexp(accE[r]);
            }
        }
    }
    // ---- PZ: wave w handles row w ----
    {
        const int r = wid;
        int b = b0 + r; b = b <= bmax ? b : bmax;
        const int sid = stu_id[b], eid = exer_id[b];   // wave-uniform
        float2 sq = *(const float2*)(stu_q + (size_t)sid * D + 2 * lane);
        float2 ek = *(const float2*)(exer_k + (size_t)eid * D + 2 * lane);
        float2 w3 = *(const float2*)(W3 + 2 * lane);
        float2 z;
        z.x = sigf(sq.x * ek.x) * fabsf(w3.x);
        z.y = sigf(sq.y * ek.y) * fabsf(w3.y);
        *(float2*)(PZf + r * D + 2 * lane) = z;
    }
    __syncthreads();   // TAB/EA/PZ ready

    // ---------------- Phase B: wave owns e in [16w,16w+16), lane owns k-pair ----
    const float4* EA4 = (const float4*)EAf;
    const float2* PZ2 = (const float2*)PZf;

    float2 acc[NB];
    #pragma unroll
    for (int r = 0; r < NB; ++r) acc[r] = make_float2(0.f, 0.f);

    #pragma unroll
    for (int jj = 0; jj < 8; ++jj) {
        const int e0 = wid * 16 + 2 * jj;
        const int j  = wid * 8 + jj;
        ushort4 h0 = TABh4[e0 * 64 + lane];        // b64 LDS read, 2-way (free)
        ushort4 h1 = TABh4[(e0 + 1) * 64 + lane];
        float4 t0 = make_float4(bf2f(h0.x), bf2f(h0.y), bf2f(h0.z), bf2f(h0.w));
        float4 t1 = make_float4(bf2f(h1.x), bf2f(h1.y), bf2f(h1.z), bf2f(h1.w));
        #pragma unroll
        for (int r = 0; r < NB; ++r) {
            float4 eA = EA4[r * 64 + j];           // wave-uniform LDS broadcast
            float2 zA = PZ2[r * 64 + j];
            CORE(eA.x, eA.y, t0, zA.x, acc[r].x, acc[r].y);
            CORE(eA.z, eA.w, t1, zA.y, acc[r].x, acc[r].y);
        }
    }
    __syncthreads();                     // all TAB reads done -> RED may alias

    float2* RED = (float2*)smemraw;      // [wave][row][lane] = 32 KB
    #pragma unroll
    for (int r = 0; r < NB; ++r)
        RED[(wid * NB + r) * 64 + lane] = acc[r];
    __syncthreads();

    // ---- cross-wave reduce + epilogue: wave w handles row w ----
    {
        const int r = wid, b = b0 + r;
        float2 s = make_float2(0.f, 0.f);
        #pragma unroll
        for (int w = 0; w < 8; ++w) {
            float2 p = RED[(w * NB + r) * 64 + lane];
            s.x += p.x; s.y += p.y;
        }
        const float b3v = b3[0];
        float o0 = sigf(s.x + b3v), o1 = sigf(s.y + b3v);
        float num = 0.f, den = 0.f;
        if (b < B) {
            float2 kqv = *(const float2*)(kq + (size_t)b * D + 2 * lane);
            num = fmaf(o0, kqv.x, o1 * kqv.y); den = kqv.x + kqv.y;
        }
        #pragma unroll
        for (int off = 32; off > 0; off >>= 1) {
            num += __shfl_xor(num, off); den += __shfl_xor(den, off);
        }
        if (lane == 0 && b < B) out[b] = num / den;
    }
}

// ---------------------------------------------------------------------------
extern "C" void kernel_launch(void* const* d_in, const int* in_sizes, int n_in,
                              void* d_out, int out_size, void* d_ws, size_t ws_size,
                              hipStream_t stream)
{
    const int*   stu_id      = (const int*)  d_in[0];
    const int*   exer_id     = (const int*)  d_in[1];
    const float* kq          = (const float*)d_in[2];
    const float* student_q   = (const float*)d_in[3];
    const float* exercise_k  = (const float*)d_in[4];
    const float* student_v   = (const float*)d_in[5];
    const float* exercise_v  = (const float*)d_in[6];
    const float* knowledge_v = (const float*)d_in[7];
    const float* W1 = (const float*)d_in[8];
    const float* b1 = (const float*)d_in[9];
    const float* W2 = (const float*)d_in[10];
    const float* b2 = (const float*)d_in[11];
    const float* W3 = (const float*)d_in[12];
    const float* b3 = (const float*)d_in[13];
    float* out = (float*)d_out;
    const int B = in_sizes[0];

    int nblk = (B + NB - 1) / NB;
    fused_kernel<<<nblk, 512, 0, stream>>>(
        stu_id, exer_id, kq, student_q, exercise_k, student_v, exercise_v,
        knowledge_v, W1, b1, W2, b2, W3, b3, out, B);
}

// Round 14
// 59.144 us; speedup vs baseline: 1.8991x; 1.8991x over previous
//
#include <hip/hip_runtime.h>

#define D  128   // EMB
#define KN 128   // K_N
#define LOG2E 1.44269504088896340736f

typedef float f32x4  __attribute__((ext_vector_type(4)));
typedef float f32x16 __attribute__((ext_vector_type(16)));
typedef short s16x8  __attribute__((ext_vector_type(8)));   // 8 bf16 (4 VGPR)

__device__ __forceinline__ float negexp(float v) {              // e^{-v}
    return __builtin_amdgcn_exp2f(v * -LOG2E);
}
__device__ __forceinline__ float sigf(float x) {                // sigmoid
    return __builtin_amdgcn_rcpf(1.0f + negexp(x));
}
__device__ __forceinline__ unsigned short f2bf(float f) {       // fp32->bf16 RNE
    unsigned u = __float_as_uint(f);
    return (unsigned short)((u + 0x7fffu + ((u >> 16) & 1u)) >> 16);
}
__device__ __forceinline__ float bf2f(unsigned short u) {
    return __uint_as_float(((unsigned)u) << 16);
}
__device__ __forceinline__ s16x8 pack8(float4 a, float4 b) {
    s16x8 r;
    r[0]=(short)f2bf(a.x); r[1]=(short)f2bf(a.y); r[2]=(short)f2bf(a.z); r[3]=(short)f2bf(a.w);
    r[4]=(short)f2bf(b.x); r[5]=(short)f2bf(b.y); r[6]=(short)f2bf(b.z); r[7]=(short)f2bf(b.w);
    return r;
}
__device__ __forceinline__ s16x8 pack8abs(float4 a, float4 b) {
    s16x8 r;
    r[0]=(short)f2bf(fabsf(a.x)); r[1]=(short)f2bf(fabsf(a.y)); r[2]=(short)f2bf(fabsf(a.z)); r[3]=(short)f2bf(fabsf(a.w));
    r[4]=(short)f2bf(fabsf(b.x)); r[5]=(short)f2bf(fabsf(b.y)); r[6]=(short)f2bf(fabsf(b.z)); r[7]=(short)f2bf(fabsf(b.w));
    return r;
}

// ---------------------------------------------------------------------------
// K1: prep GEMM -> P4g{Ea1,Ea2,pz,·} (fp32) ; trailing 8 blocks: exp tables ->
// TABg bf16 ushort[e*256 + (k>>1)*4 + (k&1) + slot] (32x32 C-layout per m74).
// 256 thr = 4 waves. No LDS, no barriers, no launch_bounds minimum.
// ---------------------------------------------------------------------------
__global__ __launch_bounds__(256) void k1_kernel(
    const int* __restrict__ stu_id, const int* __restrict__ exer_id,
    const float* __restrict__ stu_q, const float* __restrict__ exer_k,
    const float* __restrict__ stu_v, const float* __restrict__ exer_v,
    const float* __restrict__ kn,
    const float* __restrict__ W1, const float* __restrict__ b1,
    const float* __restrict__ W2, const float* __restrict__ b2,
    const float* __restrict__ W3,
    unsigned short* __restrict__ TABg, float4* __restrict__ P4g,
    int B, int nprep)
{
    const int tid  = threadIdx.x;
    const int lane = tid & 63, wid = tid >> 6;     // 4 waves
    const int l31 = lane & 31, g32 = lane >> 5;
    const int l15 = lane & 15, g16 = lane >> 4;
    const int bmax = B - 1;

    if ((int)blockIdx.x < nprep) {
        // ---- prep GEMM: 16 b's, wave handles e-tiles 2*wid, 2*wid+1 ----
        const int b0 = blockIdx.x * 16;
        int bb = b0 + l15; bb = bb <= bmax ? bb : bmax;
        const int sid_l = stu_id[bb], eid_l = exer_id[bb];
        float4 ga[8], ge[8];
        #pragma unroll
        for (int q = 0; q < 4; ++q) {
            int d = q * 32 + g16 * 8;
            const float4* pa = (const float4*)(stu_v + (size_t)sid_l * D + d);
            ga[2*q] = pa[0]; ga[2*q+1] = pa[1];
            const float4* pe = (const float4*)(exer_v + (size_t)eid_l * D + d);
            ge[2*q] = pe[0]; ge[2*q+1] = pe[1];
        }
        #pragma unroll
        for (int h = 0; h < 2; ++h) {
            const int erow = (wid * 2 + h) * 16 + l15;
            f32x4 accS = {0, 0, 0, 0}, accE = {0, 0, 0, 0};
            #pragma unroll
            for (int q = 0; q < 4; ++q) {
                int d = q * 32 + g16 * 8;
                const float4* pb = (const float4*)(W1 + (size_t)erow * (2 * D) + d);
                accS = __builtin_amdgcn_mfma_f32_16x16x32_bf16(
                    pack8(ga[2*q], ga[2*q+1]), pack8abs(pb[0], pb[1]), accS, 0, 0, 0);
                const float4* pc = (const float4*)(W2 + (size_t)erow * (2 * D) + d);
                accE = __builtin_amdgcn_mfma_f32_16x16x32_bf16(
                    pack8(ge[2*q], ge[2*q+1]), pack8abs(pc[0], pc[1]), accE, 0, 0, 0);
            }
            #pragma unroll
            for (int r = 0; r < 4; ++r) {          // C row b = g16*4+r, col e = erow
                int b = b0 + g16 * 4 + r;
                if (b <= bmax) {
                    float2 ea = make_float2(negexp(accS[r]), negexp(accE[r]));
                    *(float2*)&P4g[(size_t)b * D + erow] = ea;   // .x,.y
                }
            }
        }
        // ---- PZ: thread = (b = b0 + tid>>4, e in [(tid&15)*8, +8)) ----
        {
            int b = b0 + (tid >> 4);
            int bc = b <= bmax ? b : bmax;
            const int sid = stu_id[bc], eid = exer_id[bc];
            const int e0 = (tid & 15) * 8;
            const float4* sq4 = (const float4*)(stu_q + (size_t)sid * D + e0);
            const float4* ek4 = (const float4*)(exer_k + (size_t)eid * D + e0);
            const float4* w34 = (const float4*)(W3 + e0);
            if (b <= bmax) {
                float* Pf = (float*)P4g;
                #pragma unroll
                for (int h = 0; h < 2; ++h) {
                    float4 sq = sq4[h], ek = ek4[h], w3 = w34[h];
                    size_t base = ((size_t)b * D + e0 + 4 * h) * 4 + 2;   // .z slot
                    Pf[base + 0]  = sigf(sq.x * ek.x) * fabsf(w3.x);
                    Pf[base + 4]  = sigf(sq.y * ek.y) * fabsf(w3.y);
                    Pf[base + 8]  = sigf(sq.z * ek.z) * fabsf(w3.z);
                    Pf[base + 12] = sigf(sq.w * ek.w) * fabsf(w3.w);
                }
            }
        }
    } else {
        // ---- tables: tile id = (blk-nprep)*4 + wid in [0,32) ----
        const int id = ((int)blockIdx.x - nprep) * 4 + wid;
        const float* Wt   = (id < 16) ? W1 : W2;
        const float* bias = (id < 16) ? b1 : b2;
        const int slot = (id < 16) ? 0 : 2;
        const int et = (id >> 2) & 3, kt = id & 3;
        const int krow = kt * 32 + l31;
        const int kof  = ((krow >> 1) << 2) + (krow & 1) + slot;
        s16x8 bf[8];
        #pragma unroll
        for (int q = 0; q < 8; ++q) {
            const float4* pk = (const float4*)(kn + (size_t)krow * D + q * 16 + g32 * 8);
            bf[q] = pack8(pk[0], pk[1]);
        }
        f32x16 acc = {0};
        const int er = et * 32 + l31;
        #pragma unroll
        for (int q = 0; q < 8; ++q) {
            const float4* pw = (const float4*)(Wt + (size_t)er * (2 * D) + D + q * 16 + g32 * 8);
            acc = __builtin_amdgcn_mfma_f32_32x32x16_bf16(
                pack8abs(pw[0], pw[1]), bf[q], acc, 0, 0, 0);
        }
        #pragma unroll
        for (int r = 0; r < 16; ++r) {             // C row e, col k = krow (m74)
            int e_ = et * 32 + (r & 3) + ((r >> 2) << 3) + (g32 << 2);
            TABg[e_ * 256 + kof] = f2bf(negexp(acc[r] + bias[e_]));
        }
    }
}

// ---------------------------------------------------------------------------
// K2: streaming phase B. 1024 blocks x 256 thr (4 waves), wave owns one b,
// lane owns k = 2*lane, 2*lane+1. No LDS, no barriers, ~40 VGPR ->
// 16 waves/CU in one residency. TAB reads coalesced (512B/wave), L2-hot.
// ---------------------------------------------------------------------------
__global__ __launch_bounds__(256) void k2_kernel(
    const float4* __restrict__ P4g, const ushort4* __restrict__ TAB4,
    const float* __restrict__ kq, const float* __restrict__ b3,
    float* __restrict__ out, int B)
{
    const int tid = threadIdx.x, lane = tid & 63, wid = tid >> 6;
    const int b = blockIdx.x * 4 + wid;
    const int bc = b < B ? b : B - 1;
    const float4* Pb = P4g + (size_t)bc * D;

    float ax = 0.f, ay = 0.f;
    #pragma unroll 8
    for (int e = 0; e < D; ++e) {
        float4 p  = Pb[e];                     // wave-uniform {Ea1,Ea2,pz,·}
        ushort4 h = TAB4[e * 64 + lane];       // coalesced bf16 {E1,E1,E2,E2}
        float x0 = fmaf(p.x, bf2f(h.x), 1.0f);
        float x1 = fmaf(p.x, bf2f(h.y), 1.0f);
        float y0 = fmaf(p.y, bf2f(h.z), 1.0f);
        float y1 = fmaf(p.y, bf2f(h.w), 1.0f);
        ax = fmaf((y0 - x0) * p.z, __builtin_amdgcn_rcpf(x0 * y0), ax);
        ay = fmaf((y1 - x1) * p.z, __builtin_amdgcn_rcpf(x1 * y1), ay);
    }
    const float b3v = b3[0];
    float o0 = sigf(ax + b3v), o1 = sigf(ay + b3v);
    float2 kqv = *(const float2*)(kq + (size_t)bc * D + 2 * lane);
    float num = fmaf(o0, kqv.x, o1 * kqv.y);
    float den = kqv.x + kqv.y;
    #pragma unroll
    for (int off = 32; off > 0; off >>= 1) {
        num += __shfl_xor(num, off);
        den += __shfl_xor(den, off);
    }
    if (lane == 0 && b < B) out[b] = num / den;
}

// ---------------------------------------------------------------------------
extern "C" void kernel_launch(void* const* d_in, const int* in_sizes, int n_in,
                              void* d_out, int out_size, void* d_ws, size_t ws_size,
                              hipStream_t stream)
{
    const int*   stu_id      = (const int*)  d_in[0];
    const int*   exer_id     = (const int*)  d_in[1];
    const float* kq          = (const float*)d_in[2];
    const float* student_q   = (const float*)d_in[3];
    const float* exercise_k  = (const float*)d_in[4];
    const float* student_v   = (const float*)d_in[5];
    const float* exercise_v  = (const float*)d_in[6];
    const float* knowledge_v = (const float*)d_in[7];
    const float* W1 = (const float*)d_in[8];
    const float* b1 = (const float*)d_in[9];
    const float* W2 = (const float*)d_in[10];
    const float* b2 = (const float*)d_in[11];
    const float* W3 = (const float*)d_in[12];
    const float* b3 = (const float*)d_in[13];
    float* out = (float*)d_out;
    const int B = in_sizes[0];

    // workspace: TABg bf16 (64 KB) | P4g float4[B*128] (8 MB @ B=4096)
    unsigned short* TABg = (unsigned short*)d_ws;
    float4* P4g = (float4*)((char*)d_ws + 131072);

    const int nprep = (B + 15) / 16;
    k1_kernel<<<nprep + 8, 256, 0, stream>>>(
        stu_id, exer_id, student_q, exercise_k, student_v, exercise_v,
        knowledge_v, W1, b1, W2, b2, W3, TABg, P4g, B, nprep);
    k2_kernel<<<(B + 3) / 4, 256, 0, stream>>>(
        P4g, (const ushort4*)TABg, kq, b3, out, B);
}

// Round 15
// 37.323 us; speedup vs baseline: 3.0094x; 1.5846x over previous
//
#include <hip/hip_runtime.h>

#define D  128   // EMB
#define KN 128   // K_N
#define LOG2E 1.44269504088896340736f

typedef float f32x4  __attribute__((ext_vector_type(4)));
typedef float f32x16 __attribute__((ext_vector_type(16)));
typedef short s16x8  __attribute__((ext_vector_type(8)));   // 8 bf16 (4 VGPR)

__device__ __forceinline__ float negexp(float v) {              // e^{-v}
    return __builtin_amdgcn_exp2f(v * -LOG2E);
}
__device__ __forceinline__ float sigf(float x) {                // sigmoid
    return __builtin_amdgcn_rcpf(1.0f + negexp(x));
}
__device__ __forceinline__ unsigned short f2bf(float f) {       // fp32->bf16 RNE
    unsigned u = __float_as_uint(f);
    return (unsigned short)((u + 0x7fffu + ((u >> 16) & 1u)) >> 16);
}
__device__ __forceinline__ s16x8 pack8(float4 a, float4 b) {
    s16x8 r;
    r[0]=(short)f2bf(a.x); r[1]=(short)f2bf(a.y); r[2]=(short)f2bf(a.z); r[3]=(short)f2bf(a.w);
    r[4]=(short)f2bf(b.x); r[5]=(short)f2bf(b.y); r[6]=(short)f2bf(b.z); r[7]=(short)f2bf(b.w);
    return r;
}
__device__ __forceinline__ s16x8 pack8abs(float4 a, float4 b) {
    s16x8 r;
    r[0]=(short)f2bf(fabsf(a.x)); r[1]=(short)f2bf(fabsf(a.y)); r[2]=(short)f2bf(fabsf(a.z)); r[3]=(short)f2bf(fabsf(a.w));
    r[4]=(short)f2bf(fabsf(b.x)); r[5]=(short)f2bf(fabsf(b.y)); r[6]=(short)f2bf(fabsf(b.z)); r[7]=(short)f2bf(fabsf(b.w));
    return r;
}

// 2 k-elements for one (b,e): x'=1+Ea1*E1, y'=1+Ea2*E2; acc += (y'-x')*pz/(x'y')
#define CORE(P, T, A0, A1) do {                                              \
    float x0_ = fmaf((P).x, (T).x, 1.0f);                                    \
    float x1_ = fmaf((P).x, (T).y, 1.0f);                                    \
    float y0_ = fmaf((P).y, (T).z, 1.0f);                                    \
    float y1_ = fmaf((P).y, (T).w, 1.0f);                                    \
    (A0) = fmaf((y0_ - x0_) * (P).z, __builtin_amdgcn_rcpf(x0_ * y0_), (A0));\
    (A1) = fmaf((y1_ - x1_) * (P).z, __builtin_amdgcn_rcpf(x1_ * y1_), (A1));\
} while (0)

// ---------------------------------------------------------------------------
// K_tab: 8 blocks x 256 thr, tile id = blk*4+wid in [0,32).
// TABf fp32 [e*256 + (k>>1)*4 + (k&1) + slot], slot 0 (W1) | 2 (W2).
// 32x32 C-layout per m74: col k = lane&31, row e = (r&3)+8*(r>>2)+4*(lane>>5).
// ---------------------------------------------------------------------------
__global__ __launch_bounds__(256) void ktab_kernel(
    const float* __restrict__ kn,
    const float* __restrict__ W1, const float* __restrict__ b1,
    const float* __restrict__ W2, const float* __restrict__ b2,
    float* __restrict__ TABf)
{
    const int tid  = threadIdx.x;
    const int lane = tid & 63, wid = tid >> 6;
    const int l31 = lane & 31, g32 = lane >> 5;

    const int id = (int)blockIdx.x * 4 + wid;
    const float* Wt   = (id < 16) ? W1 : W2;
    const float* bias = (id < 16) ? b1 : b2;
    const int slot = (id < 16) ? 0 : 2;
    const int et = (id >> 2) & 3, kt = id & 3;
    const int krow = kt * 32 + l31;
    const int kof  = ((krow >> 1) << 2) + (krow & 1) + slot;

    s16x8 bf[8];
    #pragma unroll
    for (int q = 0; q < 8; ++q) {
        const float4* pk = (const float4*)(kn + (size_t)krow * D + q * 16 + g32 * 8);
        bf[q] = pack8(pk[0], pk[1]);
    }
    f32x16 acc = {0};
    const int er = et * 32 + l31;
    #pragma unroll
    for (int q = 0; q < 8; ++q) {
        const float4* pw = (const float4*)(Wt + (size_t)er * (2 * D) + D + q * 16 + g32 * 8);
        acc = __builtin_amdgcn_mfma_f32_32x32x16_bf16(
            pack8abs(pw[0], pw[1]), bf[q], acc, 0, 0, 0);
    }
    #pragma unroll
    for (int r = 0; r < 16; ++r) {
        int e_ = et * 32 + (r & 3) + ((r >> 2) << 3) + (g32 << 2);
        TABf[e_ * 256 + kof] = negexp(acc[r] + bias[e_]);
    }
}

// ---------------------------------------------------------------------------
// K_main: 512 blocks x 256 thr (4 waves), block owns 8 b's, wave owns 2 b's.
// Phase A: gathers + prep MFMA + PZ -> PA[8][128] float4 {Ea1,Ea2,pz,.} in LDS.
// Phase B: stream TAB fp32 from global (L2-hot) + 2 LDS broadcasts per e.
// 16 KB LDS, no launch_bounds cap -> high occupancy, no spill.
// ---------------------------------------------------------------------------
__global__ __launch_bounds__(256) void kmain_kernel(
    const int* __restrict__ stu_id, const int* __restrict__ exer_id,
    const float* __restrict__ kq,
    const float* __restrict__ stu_q, const float* __restrict__ exer_k,
    const float* __restrict__ stu_v, const float* __restrict__ exer_v,
    const float* __restrict__ W1, const float* __restrict__ W2,
    const float* __restrict__ W3,
    const float4* __restrict__ TAB4, const float* __restrict__ b3,
    float* __restrict__ out, int B)
{
    __shared__ float4 PA[8 * D];     // 16 KB: [b_loc][e] = {Ea1, Ea2, pz, pad}

    const int tid  = threadIdx.x;
    const int lane = tid & 63, wid = tid >> 6;
    const int l15 = lane & 15, g16 = lane >> 4;
    const int b0 = blockIdx.x * 8;
    const int bmax = B - 1;

    // ---- phase A: prep GEMM (A rows = 8 b's duplicated; e-tiles 2 per wave) ----
    {
        int bl = b0 + (l15 & 7); bl = bl <= bmax ? bl : bmax;
        const int sid_l = stu_id[bl], eid_l = exer_id[bl];
        float4 ga[8], ge[8];
        #pragma unroll
        for (int q = 0; q < 4; ++q) {
            int d = q * 32 + g16 * 8;
            const float4* pa = (const float4*)(stu_v + (size_t)sid_l * D + d);
            ga[2*q] = pa[0]; ga[2*q+1] = pa[1];
            const float4* pe = (const float4*)(exer_v + (size_t)eid_l * D + d);
            ge[2*q] = pe[0]; ge[2*q+1] = pe[1];
        }
        #pragma unroll
        for (int h = 0; h < 2; ++h) {
            const int erow = (wid * 2 + h) * 16 + l15;
            f32x4 accS = {0, 0, 0, 0}, accE = {0, 0, 0, 0};
            #pragma unroll
            for (int q = 0; q < 4; ++q) {
                int d = q * 32 + g16 * 8;
                const float4* pb = (const float4*)(W1 + (size_t)erow * (2 * D) + d);
                accS = __builtin_amdgcn_mfma_f32_16x16x32_bf16(
                    pack8(ga[2*q], ga[2*q+1]), pack8abs(pb[0], pb[1]), accS, 0, 0, 0);
                const float4* pc = (const float4*)(W2 + (size_t)erow * (2 * D) + d);
                accE = __builtin_amdgcn_mfma_f32_16x16x32_bf16(
                    pack8(ge[2*q], ge[2*q+1]), pack8abs(pc[0], pc[1]), accE, 0, 0, 0);
            }
            #pragma unroll
            for (int r = 0; r < 4; ++r) {          // C row b = g16*4+r, col e = erow
                int brow = g16 * 4 + r;
                if (brow < 8)
                    *(float2*)&PA[brow * D + erow] =
                        make_float2(negexp(accS[r]), negexp(accE[r]));
            }
        }
    }
    // ---- PZ: thread = (b_loc = tid>>5, e = (tid&31)*4 .. +4) ----
    {
        const int bloc = tid >> 5;
        int b = b0 + bloc; b = b <= bmax ? b : bmax;
        const int sid = stu_id[b], eid = exer_id[b];
        const int e0 = (tid & 31) * 4;
        float4 sq = *(const float4*)(stu_q + (size_t)sid * D + e0);
        float4 ek = *(const float4*)(exer_k + (size_t)eid * D + e0);
        float4 w3 = *(const float4*)(W3 + e0);
        float* Pf = (float*)PA;
        size_t base = ((size_t)bloc * D + e0) * 4 + 2;     // .z slots
        Pf[base + 0]  = sigf(sq.x * ek.x) * fabsf(w3.x);
        Pf[base + 4]  = sigf(sq.y * ek.y) * fabsf(w3.y);
        Pf[base + 8]  = sigf(sq.z * ek.z) * fabsf(w3.z);
        Pf[base + 12] = sigf(sq.w * ek.w) * fabsf(w3.w);
    }
    __syncthreads();

    // ---- phase B: wave owns b_loc {2wid, 2wid+1}; lane owns k = 2l, 2l+1 ----
    const float4* PAa = &PA[(2 * wid) * D];
    const float4* PAb = &PA[(2 * wid + 1) * D];

    float axA = 0.f, ayA = 0.f, axB = 0.f, ayB = 0.f;
    // depth-1 software pipeline, manual x2 unroll (named regs force ILP)
    float4 t_n  = TAB4[0 * 64 + lane];
    float4 pA_n = PAa[0], pB_n = PAb[0];
    #pragma unroll 4
    for (int e = 0; e < D; ++e) {
        float4 t  = t_n, pA = pA_n, pB = pB_n;
        if (e + 1 < D) {
            t_n  = TAB4[(e + 1) * 64 + lane];      // issue next loads first
            pA_n = PAa[e + 1];
            pB_n = PAb[e + 1];
        }
        CORE(pA, t, axA, ayA);
        CORE(pB, t, axB, ayB);
    }

    // ---- epilogue: 2 rows per wave ----
    const float b3v = b3[0];
    {
        const int bA = b0 + 2 * wid, bB = bA + 1;
        float o0a = sigf(axA + b3v), o1a = sigf(ayA + b3v);
        float o0b = sigf(axB + b3v), o1b = sigf(ayB + b3v);
        float na = 0.f, da = 0.f, nb = 0.f, db = 0.f;
        if (bA < B) {
            float2 kqa = *(const float2*)(kq + (size_t)bA * D + 2 * lane);
            na = fmaf(o0a, kqa.x, o1a * kqa.y); da = kqa.x + kqa.y;
        }
        if (bB < B) {
            float2 kqb = *(const float2*)(kq + (size_t)bB * D + 2 * lane);
            nb = fmaf(o0b, kqb.x, o1b * kqb.y); db = kqb.x + kqb.y;
        }
        #pragma unroll
        for (int off = 32; off > 0; off >>= 1) {
            na += __shfl_xor(na, off); da += __shfl_xor(da, off);
            nb += __shfl_xor(nb, off); db += __shfl_xor(db, off);
        }
        if (lane == 0) {
            if (bA < B) out[bA] = na / da;
            if (bB < B) out[bB] = nb / db;
        }
    }
}

// ---------------------------------------------------------------------------
extern "C" void kernel_launch(void* const* d_in, const int* in_sizes, int n_in,
                              void* d_out, int out_size, void* d_ws, size_t ws_size,
                              hipStream_t stream)
{
    const int*   stu_id      = (const int*)  d_in[0];
    const int*   exer_id     = (const int*)  d_in[1];
    const float* kq          = (const float*)d_in[2];
    const float* student_q   = (const float*)d_in[3];
    const float* exercise_k  = (const float*)d_in[4];
    const float* student_v   = (const float*)d_in[5];
    const float* exercise_v  = (const float*)d_in[6];
    const float* knowledge_v = (const float*)d_in[7];
    const float* W1 = (const float*)d_in[8];
    const float* b1 = (const float*)d_in[9];
    const float* W2 = (const float*)d_in[10];
    const float* b2 = (const float*)d_in[11];
    const float* W3 = (const float*)d_in[12];
    const float* b3 = (const float*)d_in[13];
    float* out = (float*)d_out;
    const int B = in_sizes[0];

    float* TABf = (float*)d_ws;    // 128 KB fp32 interleaved exp-tables

    ktab_kernel<<<8, 256, 0, stream>>>(knowledge_v, W1, b1, W2, b2, TABf);
    kmain_kernel<<<(B + 7) / 8, 256, 0, stream>>>(
        stu_id, exer_id, kq, student_q, exercise_k, student_v, exercise_v,
        W1, W2, W3, (const float4*)TABf, b3, out, B);
}